// Round 1
// baseline (5109.322 us; speedup 1.0000x reference)
//
#include <hip/hip_runtime.h>
#include <hip/hip_bf16.h>

#define BB 64
#define EE 512
#define HH 1024
#define KK 1536
#define VV 50257
#define SS 512

typedef __bf16 bf16x8 __attribute__((ext_vector_type(8)));
typedef float f32x4 __attribute__((ext_vector_type(4)));

__device__ __forceinline__ bf16x8 load_bf8(const __bf16* p) {
    return *reinterpret_cast<const bf16x8*>(p);
}

__device__ __forceinline__ bf16x8 cvt8(const float* p) {
    f32x4 a = *reinterpret_cast<const f32x4*>(p);
    f32x4 b = *reinterpret_cast<const f32x4*>(p + 4);
    bf16x8 r;
    r[0] = (__bf16)a[0]; r[1] = (__bf16)a[1]; r[2] = (__bf16)a[2]; r[3] = (__bf16)a[3];
    r[4] = (__bf16)b[0]; r[5] = (__bf16)b[1]; r[6] = (__bf16)b[2]; r[7] = (__bf16)b[3];
    return r;
}

// Decode sequence tokens to int32, auto-detecting int64 vs int32 storage.
// If int64 (little-endian, values < 2^31), every odd 32-bit word of the first
// 64 pairs is zero; for random int32 tokens that's essentially impossible.
__global__ void tokens_kernel(const void* __restrict__ seq, int* __restrict__ tok) {
    const unsigned* u = (const unsigned*)seq;
    bool is64 = true;
    #pragma unroll 1
    for (int i = 0; i < 64; ++i) {
        if (u[2 * i + 1] != 0u) { is64 = false; break; }
    }
    int i = blockIdx.x * 256 + threadIdx.x;
    if (i < BB * SS) tok[i] = is64 ? (int)u[2 * i] : (int)u[i];
}

// fp32 [R][C] row-major -> bf16 [C][R] (weights pre-transposed so MFMA
// B-fragments are contiguous 16B loads).
__global__ __launch_bounds__(256) void transpose_kernel(
    const float* __restrict__ in, __bf16* __restrict__ out, int R, int C) {
    __shared__ float t[32][33];
    int bc = C >> 5;
    int br = blockIdx.x / bc;
    int bco = blockIdx.x % bc;
    int R0 = br << 5, C0 = bco << 5;
    int c = threadIdx.x & 31, r0 = threadIdx.x >> 5;
    #pragma unroll
    for (int i = 0; i < 4; ++i) {
        int r = r0 + i * 8;
        t[r][c] = in[(size_t)(R0 + r) * C + C0 + c];
    }
    __syncthreads();
    #pragma unroll
    for (int i = 0; i < 4; ++i) {
        int r = r0 + i * 8;
        out[(size_t)(C0 + r) * R + R0 + c] = (__bf16)t[c][r];
    }
}

__global__ void init_kernel(const float* __restrict__ h1, const float* __restrict__ h2,
                            __bf16* __restrict__ h1bf, __bf16* __restrict__ h2bf) {
    int i = blockIdx.x * 256 + threadIdx.x;
    if (i < BB * HH) h1bf[i] = (__bf16)h1[i];
    if (i < BB * EE) h2bf[i] = (__bf16)h2[i];
}

// One pipelined step: blocks [0,128) compute h1^{t+1} = tanh([e_t, h1^t] W1)
// (GEMM1), blocks [128,192) compute h2^t = tanh([h1^t, h2^{t-1}] W2) (GEMM2).
// No intra-launch dependency. Tiles: 16M x 32N per WG; 4 waves split K=1536
// into quarters of 384 (each quarter a whole number of 32-wide K blocks, and
// the concat boundaries 512/1024 are 32-aligned). fp32 accumulate, LDS
// cross-wave reduce, bias + tanh in fp32, store bf16 (+fp32 on final step).
__global__ __launch_bounds__(256) void step_kernel(
    const int* __restrict__ tok32,
    const float* __restrict__ embW,
    const float* __restrict__ b1, const float* __restrict__ b2,
    const __bf16* __restrict__ W1t, const __bf16* __restrict__ W2t,
    const __bf16* __restrict__ h1cur, __bf16* __restrict__ h1next,
    const __bf16* __restrict__ h2cur, __bf16* __restrict__ h2next,
    float* __restrict__ h1f32, float* __restrict__ h2f32,
    int t, int g1, int g2) {
    const int bid = blockIdx.x;
    const bool is1 = bid < 128;
    if (is1 ? (g1 == 0) : (g2 == 0)) return;
    const int rb = is1 ? bid : (bid - 128);
    const int mi = rb & 3;
    const int ni = rb >> 2;
    const int m0 = mi << 4;
    const int n0 = ni << 5;
    const int N = is1 ? HH : EE;
    const int tid = threadIdx.x;
    const int w = tid >> 6;
    const int l = tid & 63;
    const int l16 = l & 15;
    const int kg = l >> 4;

    __shared__ int tok_s[16];
    __shared__ float red[4][16][33];

    if (is1 && tid < 16) tok_s[tid] = tok32[(m0 + tid) * SS + t];
    __syncthreads();

    const __bf16* Wt = is1 ? W1t : W2t;
    f32x4 acc0 = {0.f, 0.f, 0.f, 0.f};
    f32x4 acc1 = {0.f, 0.f, 0.f, 0.f};
    const int row = m0 + l16;
    const int kb = w * 384;

    #pragma unroll 4
    for (int kk = 0; kk < 384; kk += 32) {
        const int k = kb + kk + kg * 8;
        bf16x8 a;
        if (is1) {
            if (k < EE) a = cvt8(embW + (size_t)tok_s[l16] * EE + k);
            else        a = load_bf8(h1cur + row * HH + (k - EE));
        } else {
            if (k < HH) a = load_bf8(h1cur + row * HH + k);
            else        a = load_bf8(h2cur + row * EE + (k - HH));
        }
        bf16x8 bf0 = load_bf8(Wt + (size_t)(n0 + l16) * KK + k);
        bf16x8 bf1 = load_bf8(Wt + (size_t)(n0 + 16 + l16) * KK + k);
        acc0 = __builtin_amdgcn_mfma_f32_16x16x32_bf16(a, bf0, acc0, 0, 0, 0);
        acc1 = __builtin_amdgcn_mfma_f32_16x16x32_bf16(a, bf1, acc1, 0, 0, 0);
    }

    // D layout: col = lane&15, row = (lane>>4)*4 + reg (m89-verified)
    #pragma unroll
    for (int i = 0; i < 4; ++i) {
        red[w][kg * 4 + i][l16]      = acc0[i];
        red[w][kg * 4 + i][16 + l16] = acc1[i];
    }
    __syncthreads();

    const float* bias = is1 ? b1 : b2;
    for (int c = tid; c < 512; c += 256) {
        int m = c >> 5, n = c & 31;
        float s = red[0][m][n] + red[1][m][n] + red[2][m][n] + red[3][m][n];
        s = tanhf(s + bias[n0 + n]);
        int gi = (m0 + m) * N + (n0 + n);
        if (is1) {
            h1next[gi] = (__bf16)s;
            if (h1f32) h1f32[gi] = s;
        } else {
            h2next[gi] = (__bf16)s;
            if (h2f32) h2f32[gi] = s;
        }
    }
}

// out[64, V] = h2 @ emb_W^T + out_b. Memory-bound stream of emb_W (103 MB
// fp32); bf16 MFMA so compute hides. 64-vocab tile per WG, waves own 16 cols.
__global__ __launch_bounds__(256) void proj_kernel(
    const __bf16* __restrict__ h2bf,
    const float* __restrict__ embW,
    const float* __restrict__ outb,
    float* __restrict__ out) {
    const int v0 = blockIdx.x << 6;
    const int tid = threadIdx.x;
    const int w = tid >> 6;
    const int l = tid & 63;
    const int l16 = l & 15, kg = l >> 4;
    const int vcol = v0 + w * 16 + l16;
    const int vr = vcol < VV ? vcol : VV - 1;
    f32x4 acc[4] = {{0,0,0,0},{0,0,0,0},{0,0,0,0},{0,0,0,0}};
    #pragma unroll 2
    for (int k0 = 0; k0 < EE; k0 += 32) {
        const int k = k0 + kg * 8;
        bf16x8 bfr = cvt8(embW + (size_t)vr * EE + k);
        #pragma unroll
        for (int mf = 0; mf < 4; ++mf) {
            bf16x8 a = load_bf8(h2bf + (mf * 16 + l16) * EE + k);
            acc[mf] = __builtin_amdgcn_mfma_f32_16x16x32_bf16(a, bfr, acc[mf], 0, 0, 0);
        }
    }
    if (vcol < VV) {
        const float bb = outb[vcol];
        #pragma unroll
        for (int mf = 0; mf < 4; ++mf) {
            #pragma unroll
            for (int i = 0; i < 4; ++i) {
                int b = mf * 16 + kg * 4 + i;
                out[(size_t)b * VV + vcol] = acc[mf][i] + bb;
            }
        }
    }
}

extern "C" void kernel_launch(void* const* d_in, const int* in_sizes, int n_in,
                              void* d_out, int out_size, void* d_ws, size_t ws_size,
                              hipStream_t stream) {
    const void* seq      = d_in[0];
    const float* init_h1 = (const float*)d_in[1];
    const float* init_h2 = (const float*)d_in[2];
    const float* embW    = (const float*)d_in[3];
    const float* W1      = (const float*)d_in[4];
    const float* b1      = (const float*)d_in[5];
    const float* W2      = (const float*)d_in[6];
    const float* b2      = (const float*)d_in[7];
    const float* outb    = (const float*)d_in[8];
    float* out = (float*)d_out;

    char* ws = (char*)d_ws;
    int* tok = (int*)ws;                 ws += (size_t)BB * SS * 4;
    __bf16* W1t = (__bf16*)ws;           ws += (size_t)HH * KK * 2;
    __bf16* W2t = (__bf16*)ws;           ws += (size_t)EE * KK * 2;
    __bf16* h1b0 = (__bf16*)ws;          ws += (size_t)BB * HH * 2;
    __bf16* h1b1 = (__bf16*)ws;          ws += (size_t)BB * HH * 2;
    __bf16* h2b0 = (__bf16*)ws;          ws += (size_t)BB * EE * 2;
    __bf16* h2b1 = (__bf16*)ws;          ws += (size_t)BB * EE * 2;
    __bf16* h1bf[2] = {h1b0, h1b1};
    __bf16* h2bf[2] = {h2b0, h2b1};

    hipLaunchKernelGGL(tokens_kernel, dim3(128), dim3(256), 0, stream, seq, tok);
    hipLaunchKernelGGL(transpose_kernel, dim3((KK / 32) * (HH / 32)), dim3(256), 0, stream,
                       W1, W1t, KK, HH);
    hipLaunchKernelGGL(transpose_kernel, dim3((KK / 32) * (EE / 32)), dim3(256), 0, stream,
                       W2, W2t, KK, EE);
    hipLaunchKernelGGL(init_kernel, dim3(256), dim3(256), 0, stream,
                       init_h1, init_h2, h1b0, h2b0);

    float* h1out = out + (size_t)BB * VV;
    float* h2out = h1out + (size_t)BB * HH;

    // Launch t computes h1^{t+1} (GEMM1, t<512) and h2^{t} (GEMM2, t>=1).
    // h1^t lives in h1bf[t&1]; h2^t lives in h2bf[t&1].
    for (int t = 0; t <= SS; ++t) {
        int g1 = (t < SS) ? 1 : 0;
        int g2 = (t >= 1) ? 1 : 0;
        const __bf16* h1cur = h1bf[t & 1];
        __bf16* h1next      = h1bf[(t + 1) & 1];
        const __bf16* h2cur = h2bf[(t + 1) & 1];  // h2^{t-1}
        __bf16* h2next      = h2bf[t & 1];        // h2^{t}
        float* h1f = (t == SS - 1) ? h1out : nullptr;
        float* h2f = (t == SS) ? h2out : nullptr;
        hipLaunchKernelGGL(step_kernel, dim3(192), dim3(256), 0, stream,
                           tok, embW, b1, b2, W1t, W2t,
                           h1cur, h1next, h2cur, h2next, h1f, h2f, t, g1, g2);
    }

    hipLaunchKernelGGL(proj_kernel, dim3((VV + 63) / 64), dim3(256), 0, stream,
                       h2bf[0], embW, outb, out);
}